// Round 13
// baseline (360.256 us; speedup 1.0000x reference)
//
#include <hip/hip_runtime.h>
#include <hip/hip_bf16.h>
#include <stdint.h>

// ---------------------------------------------------------------------------
// ConvAttention (B=2,S=4096,HID=1024,H=16,HD=64; conv k=(4,1) stride=(4,1))
// inputs f32, outputs f32; internal compute bf16 (round 3: absmax 0.0625).
// Round-13: single-variable on fused_attn: phase-lock the 4 waves with ONE
// __syncthreads per 128-k section (8 total). Waves in a block read identical
// K/V sections (16KB+16KB = exactly L1); unsynced they drift -> 4x redundant
// L2 reads. Locked: wave0 L2-miss, waves1-3 L1-hit -> K/V L2 traffic
// 1.05GB -> ~0.26GB. (r6's barrier pathology was 7 barriers x 256 tiles with
// serial tid<32 sections between; this is 8 barriers total, no serial work.)
// Everything else byte-identical to round 12.
// Pipeline:
//   0. q f32 -> Xb bf16;  1. convT W* -> bf16 [N][K]
//   2a. Qh = (Xb@Wq)*exp(-lt) (head-major);  2b. Kc,Vc = conv(Xb@{Wk,Wv})
//   3. Vc -> Vct;  4. fused attn;  5. out0 = oattn @ Wlin
// ---------------------------------------------------------------------------

using short8 = __attribute__((ext_vector_type(8))) short;
using bf16x4 = __attribute__((ext_vector_type(4))) short;
using f32x4  = __attribute__((ext_vector_type(4))) float;

__device__ __forceinline__ float bf2f(short u) {
  union { float f; uint32_t i; } v; v.i = ((uint32_t)(uint16_t)u) << 16; return v.f;
}
__device__ __forceinline__ short f2bf(float f) {
  union { float f; uint32_t i; } v; v.f = f;
  uint32_t r = v.i + 0x7FFFu + ((v.i >> 16) & 1u);   // RNE
  return (short)(uint16_t)(r >> 16);
}
__device__ __forceinline__ short f2bf_hw(float f) {
  __hip_bfloat16 h = __float2bfloat16(f);             // hw cvt, pairs fuse
  return *reinterpret_cast<short*>(&h);
}

__device__ __forceinline__ void async16(const void* g, void* l) {
  __builtin_amdgcn_global_load_lds(
      (const __attribute__((address_space(1))) void*)g,
      (__attribute__((address_space(3))) void*)l, 16, 0, 0);
}

// ---------------------------------------------------------------------------
__global__ void cvt8(const float* __restrict__ in, short* __restrict__ out) {
  const size_t i = ((size_t)blockIdx.x * 256 + threadIdx.x) * 8;
  float4 a = *(const float4*)(in + i);
  float4 b = *(const float4*)(in + i + 4);
  short8 o;
  o[0] = f2bf(a.x); o[1] = f2bf(a.y); o[2] = f2bf(a.z); o[3] = f2bf(a.w);
  o[4] = f2bf(b.x); o[5] = f2bf(b.y); o[6] = f2bf(b.z); o[7] = f2bf(b.w);
  *(short8*)(out + i) = o;
}

// ---------------------------------------------------------------------------
__global__ void convT(const float* __restrict__ in, short* __restrict__ out,
                      int R, int C) {
  __shared__ float tile[64][65];
  const int c0 = blockIdx.x * 64, r0 = blockIdx.y * 64;
  const int tx = threadIdx.x & 63, ty = threadIdx.x >> 6;
  #pragma unroll
  for (int i = ty; i < 64; i += 4)
    tile[i][tx] = in[(size_t)(r0 + i) * C + c0 + tx];
  __syncthreads();
  #pragma unroll
  for (int i = ty; i < 64; i += 4)
    out[(size_t)(c0 + i) * R + r0 + tx] = f2bf(tile[tx][i]);
}

// ---------------------------------------------------------------------------
__global__ void transpose2d(const short* __restrict__ in, short* __restrict__ out,
                            int R, int C) {
  __shared__ short tile[64][65];
  const size_t zoff = (size_t)blockIdx.z * (size_t)R * (size_t)C;
  const int c0 = blockIdx.x * 64, r0 = blockIdx.y * 64;
  const int tx = threadIdx.x & 63, ty = threadIdx.x >> 6;
  #pragma unroll
  for (int i = ty; i < 64; i += 4)
    tile[i][tx] = in[zoff + (size_t)(r0 + i) * C + c0 + tx];
  __syncthreads();
  #pragma unroll
  for (int i = ty; i < 64; i += 4)
    out[zoff + (size_t)(c0 + i) * R + r0 + tx] = tile[tx][i];
}

// ---------------------------------------------------------------------------
// C = A[M][K] * Bt[N][K]^T, bf16 inputs, f32 accum. 128x128 tile, BK=64.
// mode 0: f32 row-major -> Cf ; mode 1: bf16 head-major -> C (x exp(-ltemp))
// mode 2: depthwise-conv epilogue -> (z? C2 : C)[bh][1024][64]
struct GemmArgs {
  const short* A; const short* Bt;
  short* C; short* C2; float* Cf;
  long sA, sB, sC;
  long zA, zB, zC;
  int  K;
  const float* ltemp;
  const float* cw;
  int  mode;
};

__global__ __launch_bounds__(256, 2)
void gemm_bt(GemmArgs g) {
  const int tid  = threadIdx.x;
  const int wave = tid >> 6, lane = tid & 63;
  const int l16 = lane & 15, l4 = lane >> 4;
  const int wm = wave & 1, wn = wave >> 1;
  const int m0 = blockIdx.y * 128, n0 = blockIdx.x * 128;
  const size_t zA = (size_t)blockIdx.z * g.zA;
  const size_t zB = (size_t)blockIdx.z * g.zB;
  const size_t zC = (size_t)blockIdx.z * g.zC;

  __shared__ __align__(16) short As[128 * 64];
  __shared__ __align__(16) short Bs[128 * 64];

  f32x4 acc[4][4] = {};

  const int srow = tid >> 3;
  const int scol = (tid & 7) << 3;
  const short* Abase = g.A + zA + (size_t)m0 * g.sA + scol;
  const short* Bbase = g.Bt + zB + (size_t)n0 * g.sB + scol;

  for (int k0 = 0; k0 < g.K; k0 += 64) {
    __syncthreads();
    #pragma unroll
    for (int c = 0; c < 4; ++c) {
      async16(Abase + (size_t)(c * 32 + srow) * g.sA + k0, &As[c * 2048 + wave * 512]);
      async16(Bbase + (size_t)(c * 32 + srow) * g.sB + k0, &Bs[c * 2048 + wave * 512]);
    }
    asm volatile("s_waitcnt vmcnt(0)" ::: "memory");
    __syncthreads();
    #pragma unroll
    for (int kk = 0; kk < 2; ++kk) {
      short8 a[4], b[4];
      #pragma unroll
      for (int t = 0; t < 4; ++t) {
        a[t] = *(const short8*)&As[(wm * 64 + t * 16 + l16) * 64 + kk * 32 + l4 * 8];
        b[t] = *(const short8*)&Bs[(wn * 64 + t * 16 + l16) * 64 + kk * 32 + l4 * 8];
      }
      #pragma unroll
      for (int i = 0; i < 4; ++i)
        #pragma unroll
        for (int j = 0; j < 4; ++j)
          acc[i][j] = __builtin_amdgcn_mfma_f32_16x16x32_bf16(a[i], b[j], acc[i][j], 0, 0, 0);
    }
  }

  if (g.mode == 0) {
    float* Cz = g.Cf + zC;
    #pragma unroll
    for (int i = 0; i < 4; ++i) {
      const int row = m0 + wm * 64 + i * 16 + l4 * 4;
      #pragma unroll
      for (int j = 0; j < 4; ++j) {
        const int col = n0 + wn * 64 + j * 16 + l16;
        #pragma unroll
        for (int rr = 0; rr < 4; ++rr)
          Cz[(size_t)(row + rr) * g.sC + col] = acc[i][j][rr];
      }
    }
  } else if (g.mode == 1) {
    float sc = 1.0f;
    if (g.ltemp) sc = __expf(-g.ltemp[0]);
    short* Cz = g.C + zC;
    #pragma unroll
    for (int i = 0; i < 4; ++i) {
      const int row = m0 + wm * 64 + i * 16 + l4 * 4;
      #pragma unroll
      for (int j = 0; j < 4; ++j) {
        const int col = n0 + wn * 64 + j * 16 + l16;
        const int hh = col >> 6, dd = col & 63;
        #pragma unroll
        for (int rr = 0; rr < 4; ++rr) {
          const int m = row + rr;
          const size_t off = (size_t)((m >> 12) * 16 + hh) * 262144
                           + (size_t)(m & 4095) * 64 + dd;
          Cz[off] = f2bf(acc[i][j][rr] * sc);
        }
      }
    }
  } else {
    const int h = (n0 + wn * 64) >> 6;
    float wv[4];
    #pragma unroll
    for (int t = 0; t < 4; ++t) wv[t] = g.cw[h * 4 + t];
    short* dst = blockIdx.z ? g.C2 : g.C;
    #pragma unroll
    for (int i = 0; i < 4; ++i) {
      const int row_base = m0 + wm * 64 + i * 16 + l4 * 4;
      const int b  = row_base >> 12;
      const int sk = (row_base & 4095) >> 2;
      #pragma unroll
      for (int j = 0; j < 4; ++j) {
        const int d = j * 16 + l16;
        float v = wv[0] * acc[i][j][0] + wv[1] * acc[i][j][1]
                + wv[2] * acc[i][j][2] + wv[3] * acc[i][j][3];
        dst[(size_t)(b * 16 + h) * 65536 + (size_t)sk * 64 + d] = f2bf(v);
      }
    }
  }
}

// ---------------------------------------------------------------------------
// fused logits + max-free softmax + PV. Wave-private LDS; ONE barrier per
// 128-k section (phase-locks the 4 waves so their identical K/V section
// reads hit L1 instead of 4x L2).
// 1-D grid 1024: bh = id&31 (XCD-pinned), qt = id>>5. Block = 128 q-rows;
// wave owns 32 q (two 16-row strips A/B) x full k=1024 in 8 sections of 128.
__global__ __launch_bounds__(256, 4)
void fused_attn(const short* __restrict__ qh, const short* __restrict__ kc,
                const short* __restrict__ vct,
                float* __restrict__ logits, short* __restrict__ oattn) {
  const int id = blockIdx.x;
  const int bh = id & 31;                 // XCD-pinned: id%8 == bh%8
  const int qt = id >> 5;
  const int tid = threadIdx.x;
  const int wave = tid >> 6, lane = tid & 63;
  const int l16 = lane & 15, l4 = lane >> 4;

  __shared__ __align__(16) short attb[4][32 * 128];   // P bf16, 8KB/wave
  short* const myatt = attb[wave];

  const int qg = qt * 128 + wave * 32;    // wave's q-row base (32 rows)

  const short* qbase = qh + (size_t)bh * 262144 + (size_t)qg * 64;
  const short8 aQ0_0 = *(const short8*)(qbase + (size_t)l16 * 64 + l4 * 8);
  const short8 aQ0_1 = *(const short8*)(qbase + (size_t)l16 * 64 + 32 + l4 * 8);
  const short8 aQ1_0 = *(const short8*)(qbase + (size_t)(16 + l16) * 64 + l4 * 8);
  const short8 aQ1_1 = *(const short8*)(qbase + (size_t)(16 + l16) * 64 + 32 + l4 * 8);

  const short* kb = kc + (size_t)bh * 65536;
  const short* vb = vct + (size_t)bh * 65536;
  float* lgqA = logits + (size_t)bh * 4194304 + (size_t)(qg + l16) * 1024;
  float* lgqB = lgqA + 16 * 1024;

  const int sw = (l16 & 7) << 3;          // same for rows l16 and 16+l16
  float psumA = 0.f, psumB = 0.f;
  f32x4 o0 = {}, o1 = {}, o2 = {}, o3 = {};
  f32x4 o4 = {}, o5 = {}, o6 = {}, o7 = {};

  for (int sec = 0; sec < 8; ++sec) {
    const int kbase = sec * 128;
    __syncthreads();                      // phase-lock waves: shared K/V
                                          // section stays L1-resident

    #pragma unroll 2
    for (int j = 0; j < 8; ++j) {
      const int kr = kbase + j * 16 + l16;
      short8 k0 = *(const short8*)(kb + (size_t)kr * 64 + l4 * 8);
      short8 k1 = *(const short8*)(kb + (size_t)kr * 64 + 32 + l4 * 8);
      f32x4 accA = {}, accB = {};
      accA = __builtin_amdgcn_mfma_f32_16x16x32_bf16(k0, aQ0_0, accA, 0, 0, 0);
      accA = __builtin_amdgcn_mfma_f32_16x16x32_bf16(k1, aQ0_1, accA, 0, 0, 0);
      accB = __builtin_amdgcn_mfma_f32_16x16x32_bf16(k0, aQ1_0, accB, 0, 0, 0);
      accB = __builtin_amdgcn_mfma_f32_16x16x32_bf16(k1, aQ1_1, accB, 0, 0, 0);

      // logits[q][k=kbase+j*16+l4*4..+3], 16B/lane, j-adjacent fills lines
      __builtin_nontemporal_store(accA, (f32x4*)(lgqA + kbase + j * 16 + l4 * 4));
      __builtin_nontemporal_store(accB, (f32x4*)(lgqB + kbase + j * 16 + l4 * 4));

      bf16x4 pA, pB;
      #pragma unroll
      for (int rr = 0; rr < 4; ++rr) {
        const float eA = __expf(accA[rr]);
        const float eB = __expf(accB[rr]);
        psumA += eA;
        psumB += eB;
        pA[rr] = f2bf_hw(eA);
        pB[rr] = f2bf_hw(eB);
      }
      const int pc = (j * 16 + l4 * 4) ^ sw;
      *(bf16x4*)&myatt[l16 * 128 + pc] = pA;
      *(bf16x4*)&myatt[(16 + l16) * 128 + pc] = pB;
    }

    // ---- PV over this 128-k section (V loads shared by both strips) ----
    #pragma unroll
    for (int c = 0; c < 4; ++c) {
      const int cb = kbase + c * 32 + l4 * 8;
      const int cl = (c * 32 + l4 * 8) ^ sw;
      short8 paA = *(const short8*)&myatt[l16 * 128 + cl];
      short8 paB = *(const short8*)&myatt[(16 + l16) * 128 + cl];
      short8 v0 = *(const short8*)(vb + (size_t)(l16)      * 1024 + cb);
      short8 v1 = *(const short8*)(vb + (size_t)(16 + l16) * 1024 + cb);
      short8 v2 = *(const short8*)(vb + (size_t)(32 + l16) * 1024 + cb);
      short8 v3 = *(const short8*)(vb + (size_t)(48 + l16) * 1024 + cb);
      o0 = __builtin_amdgcn_mfma_f32_16x16x32_bf16(paA, v0, o0, 0, 0, 0);
      o1 = __builtin_amdgcn_mfma_f32_16x16x32_bf16(paA, v1, o1, 0, 0, 0);
      o2 = __builtin_amdgcn_mfma_f32_16x16x32_bf16(paA, v2, o2, 0, 0, 0);
      o3 = __builtin_amdgcn_mfma_f32_16x16x32_bf16(paA, v3, o3, 0, 0, 0);
      o4 = __builtin_amdgcn_mfma_f32_16x16x32_bf16(paB, v0, o4, 0, 0, 0);
      o5 = __builtin_amdgcn_mfma_f32_16x16x32_bf16(paB, v1, o5, 0, 0, 0);
      o6 = __builtin_amdgcn_mfma_f32_16x16x32_bf16(paB, v2, o6, 0, 0, 0);
      o7 = __builtin_amdgcn_mfma_f32_16x16x32_bf16(paB, v3, o7, 0, 0, 0);
    }
  }

  // rowsums: lane covers q=l16 (A) / q=16+l16 (B); combine l4 groups
  psumA += __shfl_xor(psumA, 16, 64);
  psumA += __shfl_xor(psumA, 32, 64);
  psumB += __shfl_xor(psumB, 16, 64);
  psumB += __shfl_xor(psumB, 32, 64);
  float invA[4], invB[4];
  #pragma unroll
  for (int rr = 0; rr < 4; ++rr) {
    invA[rr] = 1.0f / __shfl(psumA, l4 * 4 + rr, 64);
    invB[rr] = 1.0f / __shfl(psumB, l4 * 4 + rr, 64);
  }

  // O[q local = (strip*16)+l4*4+rr][d = n*16+l16]
  short* op = oattn + ((size_t)(bh >> 4) * 4096 + qg) * 1024 + (bh & 15) * 64;
  #pragma unroll
  for (int rr = 0; rr < 4; ++rr) {
    const size_t ra = (size_t)(l4 * 4 + rr) * 1024;
    op[ra + l16]      = f2bf(o0[rr] * invA[rr]);
    op[ra + 16 + l16] = f2bf(o1[rr] * invA[rr]);
    op[ra + 32 + l16] = f2bf(o2[rr] * invA[rr]);
    op[ra + 48 + l16] = f2bf(o3[rr] * invA[rr]);
    const size_t rb = (size_t)(16 + l4 * 4 + rr) * 1024;
    op[rb + l16]      = f2bf(o4[rr] * invB[rr]);
    op[rb + 16 + l16] = f2bf(o5[rr] * invB[rr]);
    op[rb + 32 + l16] = f2bf(o6[rr] * invB[rr]);
    op[rb + 48 + l16] = f2bf(o7[rr] * invB[rr]);
  }
}

// ---------------------------------------------------------------------------
extern "C" void kernel_launch(void* const* d_in, const int* in_sizes, int n_in,
                              void* d_out, int out_size, void* d_ws, size_t ws_size,
                              hipStream_t stream) {
  const float* q    = (const float*)d_in[0];
  const float* Wq   = (const float*)d_in[1];
  const float* Wk   = (const float*)d_in[2];
  const float* Wv   = (const float*)d_in[3];
  const float* Wlin = (const float*)d_in[4];
  const float* cw   = (const float*)d_in[5];
  const float* lt   = (const float*)d_in[6];

  float* out_f    = (float*)d_out;             // output 0: [8192][1024] f32
  float* logits_f = out_f + 8388608;           // output 1: [32][4096][1024] f32

  short* ws    = (short*)d_ws;
  short* Wt    = ws;                 // 4 x 1048576
  short* Xb    = ws + 4194304;       // 8388608 ; reused as oattn
  short* QKVq  = ws + 12582912;      // 8388608 head-major Q (pre-scaled)
  short* Kc    = ws + 20971520;      // [32][1024][64]
  short* Vc    = ws + 23068672;      // [32][1024][64]
  short* Vct   = ws + 25165824;      // [32][64][1024]
  short* oattn = Xb;
  // total 27,262,976 shorts = 54.5 MB

  cvt8<<<dim3(4096), 256, 0, stream>>>(q, Xb);

  convT<<<dim3(16, 16), 256, 0, stream>>>(Wq,   Wt,           1024, 1024);
  convT<<<dim3(16, 16), 256, 0, stream>>>(Wk,   Wt + 1048576, 1024, 1024);
  convT<<<dim3(16, 16), 256, 0, stream>>>(Wv,   Wt + 2097152, 1024, 1024);
  convT<<<dim3(16, 16), 256, 0, stream>>>(Wlin, Wt + 3145728, 1024, 1024);

  // Q projection (head-major epilogue, pre-scaled by exp(-log_temp))
  GemmArgs gq = {};
  gq.A = Xb; gq.Bt = Wt; gq.C = QKVq;
  gq.sA = 1024; gq.sB = 1024; gq.sC = 0;
  gq.zA = 0; gq.zB = 0; gq.zC = 0;
  gq.K = 1024; gq.ltemp = lt; gq.mode = 1;
  gemm_bt<<<dim3(8, 64, 1), 256, 0, stream>>>(gq);

  // K,V projections with fused depthwise conv (z=0 -> Kc, z=1 -> Vc)
  GemmArgs gkv = {};
  gkv.A = Xb; gkv.Bt = Wt + 1048576; gkv.C = Kc; gkv.C2 = Vc;
  gkv.sA = 1024; gkv.sB = 1024; gkv.sC = 0;
  gkv.zA = 0; gkv.zB = 1048576; gkv.zC = 0;
  gkv.K = 1024; gkv.cw = cw; gkv.mode = 2;
  gemm_bt<<<dim3(8, 64, 2), 256, 0, stream>>>(gkv);

  // Vc -> Vct
  transpose2d<<<dim3(1, 16, 32), 256, 0, stream>>>(Vc, Vct, 1024, 64);

  // fused logits (nt f32) + max-free softmax + PV; 32 q/wave, phase-locked
  fused_attn<<<dim3(1024), 256, 0, stream>>>(QKVq, Kc, Vct, logits_f, oattn);

  // out = oattn @ Wlin
  GemmArgs gf = {};
  gf.A = oattn; gf.Bt = Wt + 3145728; gf.Cf = out_f;
  gf.sA = 1024; gf.sB = 1024; gf.sC = 1024;
  gf.zA = 0; gf.zB = 0; gf.zC = 0;
  gf.K = 1024; gf.mode = 0;
  gemm_bt<<<dim3(8, 64, 1), 256, 0, stream>>>(gf);
}

// Round 14
// 340.948 us; speedup vs baseline: 1.0566x; 1.0566x over previous
//
#include <hip/hip_runtime.h>
#include <hip/hip_bf16.h>
#include <stdint.h>

// ---------------------------------------------------------------------------
// ConvAttention (B=2,S=4096,HID=1024,H=16,HD=64; conv k=(4,1) stride=(4,1))
// inputs f32, outputs f32; internal compute bf16 (round 3: absmax 0.0625).
// Round-14: A/B vs r12 baseline: drop __builtin_nontemporal_store -> plain
// f32x4 stores. Evidence: harness fill kernels sustain 6.5TB/s of PLAIN
// stores through L2; our nt stores run 2.6TB/s. Since r8 the logit stores
// complete full 128B lines (j-pairs), so L2 write-combining needs no RMW
// fetch -- nt's raison d'etre is gone, and nt bypasses L2's combining
// buffers (lower drain rate; stores share vmcnt with loads -> store latency
// lands on the K-load wait chain). r13's phase-lock barrier reverted (null).
// Pipeline:
//   0. q f32 -> Xb bf16;  1. convT W* -> bf16 [N][K]
//   2a. Qh = (Xb@Wq)*exp(-lt) (head-major);  2b. Kc,Vc = conv(Xb@{Wk,Wv})
//   3. Vc -> Vct;  4. fused attn;  5. out0 = oattn @ Wlin
// ---------------------------------------------------------------------------

using short8 = __attribute__((ext_vector_type(8))) short;
using bf16x4 = __attribute__((ext_vector_type(4))) short;
using f32x4  = __attribute__((ext_vector_type(4))) float;

__device__ __forceinline__ float bf2f(short u) {
  union { float f; uint32_t i; } v; v.i = ((uint32_t)(uint16_t)u) << 16; return v.f;
}
__device__ __forceinline__ short f2bf(float f) {
  union { float f; uint32_t i; } v; v.f = f;
  uint32_t r = v.i + 0x7FFFu + ((v.i >> 16) & 1u);   // RNE
  return (short)(uint16_t)(r >> 16);
}
__device__ __forceinline__ short f2bf_hw(float f) {
  __hip_bfloat16 h = __float2bfloat16(f);             // hw cvt, pairs fuse
  return *reinterpret_cast<short*>(&h);
}

__device__ __forceinline__ void async16(const void* g, void* l) {
  __builtin_amdgcn_global_load_lds(
      (const __attribute__((address_space(1))) void*)g,
      (__attribute__((address_space(3))) void*)l, 16, 0, 0);
}

// ---------------------------------------------------------------------------
__global__ void cvt8(const float* __restrict__ in, short* __restrict__ out) {
  const size_t i = ((size_t)blockIdx.x * 256 + threadIdx.x) * 8;
  float4 a = *(const float4*)(in + i);
  float4 b = *(const float4*)(in + i + 4);
  short8 o;
  o[0] = f2bf(a.x); o[1] = f2bf(a.y); o[2] = f2bf(a.z); o[3] = f2bf(a.w);
  o[4] = f2bf(b.x); o[5] = f2bf(b.y); o[6] = f2bf(b.z); o[7] = f2bf(b.w);
  *(short8*)(out + i) = o;
}

// ---------------------------------------------------------------------------
__global__ void convT(const float* __restrict__ in, short* __restrict__ out,
                      int R, int C) {
  __shared__ float tile[64][65];
  const int c0 = blockIdx.x * 64, r0 = blockIdx.y * 64;
  const int tx = threadIdx.x & 63, ty = threadIdx.x >> 6;
  #pragma unroll
  for (int i = ty; i < 64; i += 4)
    tile[i][tx] = in[(size_t)(r0 + i) * C + c0 + tx];
  __syncthreads();
  #pragma unroll
  for (int i = ty; i < 64; i += 4)
    out[(size_t)(c0 + i) * R + r0 + tx] = f2bf(tile[tx][i]);
}

// ---------------------------------------------------------------------------
__global__ void transpose2d(const short* __restrict__ in, short* __restrict__ out,
                            int R, int C) {
  __shared__ short tile[64][65];
  const size_t zoff = (size_t)blockIdx.z * (size_t)R * (size_t)C;
  const int c0 = blockIdx.x * 64, r0 = blockIdx.y * 64;
  const int tx = threadIdx.x & 63, ty = threadIdx.x >> 6;
  #pragma unroll
  for (int i = ty; i < 64; i += 4)
    tile[i][tx] = in[zoff + (size_t)(r0 + i) * C + c0 + tx];
  __syncthreads();
  #pragma unroll
  for (int i = ty; i < 64; i += 4)
    out[zoff + (size_t)(c0 + i) * R + r0 + tx] = tile[tx][i];
}

// ---------------------------------------------------------------------------
// C = A[M][K] * Bt[N][K]^T, bf16 inputs, f32 accum. 128x128 tile, BK=64.
// mode 0: f32 row-major -> Cf ; mode 1: bf16 head-major -> C (x exp(-ltemp))
// mode 2: depthwise-conv epilogue -> (z? C2 : C)[bh][1024][64]
struct GemmArgs {
  const short* A; const short* Bt;
  short* C; short* C2; float* Cf;
  long sA, sB, sC;
  long zA, zB, zC;
  int  K;
  const float* ltemp;
  const float* cw;
  int  mode;
};

__global__ __launch_bounds__(256, 2)
void gemm_bt(GemmArgs g) {
  const int tid  = threadIdx.x;
  const int wave = tid >> 6, lane = tid & 63;
  const int l16 = lane & 15, l4 = lane >> 4;
  const int wm = wave & 1, wn = wave >> 1;
  const int m0 = blockIdx.y * 128, n0 = blockIdx.x * 128;
  const size_t zA = (size_t)blockIdx.z * g.zA;
  const size_t zB = (size_t)blockIdx.z * g.zB;
  const size_t zC = (size_t)blockIdx.z * g.zC;

  __shared__ __align__(16) short As[128 * 64];
  __shared__ __align__(16) short Bs[128 * 64];

  f32x4 acc[4][4] = {};

  const int srow = tid >> 3;
  const int scol = (tid & 7) << 3;
  const short* Abase = g.A + zA + (size_t)m0 * g.sA + scol;
  const short* Bbase = g.Bt + zB + (size_t)n0 * g.sB + scol;

  for (int k0 = 0; k0 < g.K; k0 += 64) {
    __syncthreads();
    #pragma unroll
    for (int c = 0; c < 4; ++c) {
      async16(Abase + (size_t)(c * 32 + srow) * g.sA + k0, &As[c * 2048 + wave * 512]);
      async16(Bbase + (size_t)(c * 32 + srow) * g.sB + k0, &Bs[c * 2048 + wave * 512]);
    }
    asm volatile("s_waitcnt vmcnt(0)" ::: "memory");
    __syncthreads();
    #pragma unroll
    for (int kk = 0; kk < 2; ++kk) {
      short8 a[4], b[4];
      #pragma unroll
      for (int t = 0; t < 4; ++t) {
        a[t] = *(const short8*)&As[(wm * 64 + t * 16 + l16) * 64 + kk * 32 + l4 * 8];
        b[t] = *(const short8*)&Bs[(wn * 64 + t * 16 + l16) * 64 + kk * 32 + l4 * 8];
      }
      #pragma unroll
      for (int i = 0; i < 4; ++i)
        #pragma unroll
        for (int j = 0; j < 4; ++j)
          acc[i][j] = __builtin_amdgcn_mfma_f32_16x16x32_bf16(a[i], b[j], acc[i][j], 0, 0, 0);
    }
  }

  if (g.mode == 0) {
    float* Cz = g.Cf + zC;
    #pragma unroll
    for (int i = 0; i < 4; ++i) {
      const int row = m0 + wm * 64 + i * 16 + l4 * 4;
      #pragma unroll
      for (int j = 0; j < 4; ++j) {
        const int col = n0 + wn * 64 + j * 16 + l16;
        #pragma unroll
        for (int rr = 0; rr < 4; ++rr)
          Cz[(size_t)(row + rr) * g.sC + col] = acc[i][j][rr];
      }
    }
  } else if (g.mode == 1) {
    float sc = 1.0f;
    if (g.ltemp) sc = __expf(-g.ltemp[0]);
    short* Cz = g.C + zC;
    #pragma unroll
    for (int i = 0; i < 4; ++i) {
      const int row = m0 + wm * 64 + i * 16 + l4 * 4;
      #pragma unroll
      for (int j = 0; j < 4; ++j) {
        const int col = n0 + wn * 64 + j * 16 + l16;
        const int hh = col >> 6, dd = col & 63;
        #pragma unroll
        for (int rr = 0; rr < 4; ++rr) {
          const int m = row + rr;
          const size_t off = (size_t)((m >> 12) * 16 + hh) * 262144
                           + (size_t)(m & 4095) * 64 + dd;
          Cz[off] = f2bf(acc[i][j][rr] * sc);
        }
      }
    }
  } else {
    const int h = (n0 + wn * 64) >> 6;
    float wv[4];
    #pragma unroll
    for (int t = 0; t < 4; ++t) wv[t] = g.cw[h * 4 + t];
    short* dst = blockIdx.z ? g.C2 : g.C;
    #pragma unroll
    for (int i = 0; i < 4; ++i) {
      const int row_base = m0 + wm * 64 + i * 16 + l4 * 4;
      const int b  = row_base >> 12;
      const int sk = (row_base & 4095) >> 2;
      #pragma unroll
      for (int j = 0; j < 4; ++j) {
        const int d = j * 16 + l16;
        float v = wv[0] * acc[i][j][0] + wv[1] * acc[i][j][1]
                + wv[2] * acc[i][j][2] + wv[3] * acc[i][j][3];
        dst[(size_t)(b * 16 + h) * 65536 + (size_t)sk * 64 + d] = f2bf(v);
      }
    }
  }
}

// ---------------------------------------------------------------------------
// fused logits + max-free softmax + PV. ZERO barriers, wave-private LDS.
// 1-D grid 1024: bh = id&31 (XCD-pinned), qt = id>>5. Block = 128 q-rows;
// wave owns 32 q (two 16-row strips A/B) x full k=1024 in 8 sections of 128.
// Logit stores: PLAIN f32x4 through L2 (full 128B lines via j-pairs ->
// write-combine, no RMW; fills prove 6.5TB/s on this path).
__global__ __launch_bounds__(256, 4)
void fused_attn(const short* __restrict__ qh, const short* __restrict__ kc,
                const short* __restrict__ vct,
                float* __restrict__ logits, short* __restrict__ oattn) {
  const int id = blockIdx.x;
  const int bh = id & 31;                 // XCD-pinned: id%8 == bh%8
  const int qt = id >> 5;
  const int tid = threadIdx.x;
  const int wave = tid >> 6, lane = tid & 63;
  const int l16 = lane & 15, l4 = lane >> 4;

  __shared__ __align__(16) short attb[4][32 * 128];   // P bf16, 8KB/wave
  short* const myatt = attb[wave];

  const int qg = qt * 128 + wave * 32;    // wave's q-row base (32 rows)

  const short* qbase = qh + (size_t)bh * 262144 + (size_t)qg * 64;
  const short8 aQ0_0 = *(const short8*)(qbase + (size_t)l16 * 64 + l4 * 8);
  const short8 aQ0_1 = *(const short8*)(qbase + (size_t)l16 * 64 + 32 + l4 * 8);
  const short8 aQ1_0 = *(const short8*)(qbase + (size_t)(16 + l16) * 64 + l4 * 8);
  const short8 aQ1_1 = *(const short8*)(qbase + (size_t)(16 + l16) * 64 + 32 + l4 * 8);

  const short* kb = kc + (size_t)bh * 65536;
  const short* vb = vct + (size_t)bh * 65536;
  float* lgqA = logits + (size_t)bh * 4194304 + (size_t)(qg + l16) * 1024;
  float* lgqB = lgqA + 16 * 1024;

  const int sw = (l16 & 7) << 3;          // same for rows l16 and 16+l16
  float psumA = 0.f, psumB = 0.f;
  f32x4 o0 = {}, o1 = {}, o2 = {}, o3 = {};
  f32x4 o4 = {}, o5 = {}, o6 = {}, o7 = {};

  for (int sec = 0; sec < 8; ++sec) {
    const int kbase = sec * 128;

    #pragma unroll 2
    for (int j = 0; j < 8; ++j) {
      const int kr = kbase + j * 16 + l16;
      short8 k0 = *(const short8*)(kb + (size_t)kr * 64 + l4 * 8);
      short8 k1 = *(const short8*)(kb + (size_t)kr * 64 + 32 + l4 * 8);
      f32x4 accA = {}, accB = {};
      accA = __builtin_amdgcn_mfma_f32_16x16x32_bf16(k0, aQ0_0, accA, 0, 0, 0);
      accA = __builtin_amdgcn_mfma_f32_16x16x32_bf16(k1, aQ0_1, accA, 0, 0, 0);
      accB = __builtin_amdgcn_mfma_f32_16x16x32_bf16(k0, aQ1_0, accB, 0, 0, 0);
      accB = __builtin_amdgcn_mfma_f32_16x16x32_bf16(k1, aQ1_1, accB, 0, 0, 0);

      // logits[q][k=kbase+j*16+l4*4..+3], 16B/lane, j-adjacent fills lines;
      // PLAIN stores (L2 write-combining path, no RMW on full lines)
      *(f32x4*)(lgqA + kbase + j * 16 + l4 * 4) = accA;
      *(f32x4*)(lgqB + kbase + j * 16 + l4 * 4) = accB;

      bf16x4 pA, pB;
      #pragma unroll
      for (int rr = 0; rr < 4; ++rr) {
        const float eA = __expf(accA[rr]);
        const float eB = __expf(accB[rr]);
        psumA += eA;
        psumB += eB;
        pA[rr] = f2bf_hw(eA);
        pB[rr] = f2bf_hw(eB);
      }
      const int pc = (j * 16 + l4 * 4) ^ sw;
      *(bf16x4*)&myatt[l16 * 128 + pc] = pA;
      *(bf16x4*)&myatt[(16 + l16) * 128 + pc] = pB;
    }

    // ---- PV over this 128-k section (V loads shared by both strips) ----
    #pragma unroll
    for (int c = 0; c < 4; ++c) {
      const int cb = kbase + c * 32 + l4 * 8;
      const int cl = (c * 32 + l4 * 8) ^ sw;
      short8 paA = *(const short8*)&myatt[l16 * 128 + cl];
      short8 paB = *(const short8*)&myatt[(16 + l16) * 128 + cl];
      short8 v0 = *(const short8*)(vb + (size_t)(l16)      * 1024 + cb);
      short8 v1 = *(const short8*)(vb + (size_t)(16 + l16) * 1024 + cb);
      short8 v2 = *(const short8*)(vb + (size_t)(32 + l16) * 1024 + cb);
      short8 v3 = *(const short8*)(vb + (size_t)(48 + l16) * 1024 + cb);
      o0 = __builtin_amdgcn_mfma_f32_16x16x32_bf16(paA, v0, o0, 0, 0, 0);
      o1 = __builtin_amdgcn_mfma_f32_16x16x32_bf16(paA, v1, o1, 0, 0, 0);
      o2 = __builtin_amdgcn_mfma_f32_16x16x32_bf16(paA, v2, o2, 0, 0, 0);
      o3 = __builtin_amdgcn_mfma_f32_16x16x32_bf16(paA, v3, o3, 0, 0, 0);
      o4 = __builtin_amdgcn_mfma_f32_16x16x32_bf16(paB, v0, o4, 0, 0, 0);
      o5 = __builtin_amdgcn_mfma_f32_16x16x32_bf16(paB, v1, o5, 0, 0, 0);
      o6 = __builtin_amdgcn_mfma_f32_16x16x32_bf16(paB, v2, o6, 0, 0, 0);
      o7 = __builtin_amdgcn_mfma_f32_16x16x32_bf16(paB, v3, o7, 0, 0, 0);
    }
  }

  // rowsums: lane covers q=l16 (A) / q=16+l16 (B); combine l4 groups
  psumA += __shfl_xor(psumA, 16, 64);
  psumA += __shfl_xor(psumA, 32, 64);
  psumB += __shfl_xor(psumB, 16, 64);
  psumB += __shfl_xor(psumB, 32, 64);
  float invA[4], invB[4];
  #pragma unroll
  for (int rr = 0; rr < 4; ++rr) {
    invA[rr] = 1.0f / __shfl(psumA, l4 * 4 + rr, 64);
    invB[rr] = 1.0f / __shfl(psumB, l4 * 4 + rr, 64);
  }

  // O[q local = (strip*16)+l4*4+rr][d = n*16+l16]
  short* op = oattn + ((size_t)(bh >> 4) * 4096 + qg) * 1024 + (bh & 15) * 64;
  #pragma unroll
  for (int rr = 0; rr < 4; ++rr) {
    const size_t ra = (size_t)(l4 * 4 + rr) * 1024;
    op[ra + l16]      = f2bf(o0[rr] * invA[rr]);
    op[ra + 16 + l16] = f2bf(o1[rr] * invA[rr]);
    op[ra + 32 + l16] = f2bf(o2[rr] * invA[rr]);
    op[ra + 48 + l16] = f2bf(o3[rr] * invA[rr]);
    const size_t rb = (size_t)(16 + l4 * 4 + rr) * 1024;
    op[rb + l16]      = f2bf(o4[rr] * invB[rr]);
    op[rb + 16 + l16] = f2bf(o5[rr] * invB[rr]);
    op[rb + 32 + l16] = f2bf(o6[rr] * invB[rr]);
    op[rb + 48 + l16] = f2bf(o7[rr] * invB[rr]);
  }
}

// ---------------------------------------------------------------------------
extern "C" void kernel_launch(void* const* d_in, const int* in_sizes, int n_in,
                              void* d_out, int out_size, void* d_ws, size_t ws_size,
                              hipStream_t stream) {
  const float* q    = (const float*)d_in[0];
  const float* Wq   = (const float*)d_in[1];
  const float* Wk   = (const float*)d_in[2];
  const float* Wv   = (const float*)d_in[3];
  const float* Wlin = (const float*)d_in[4];
  const float* cw   = (const float*)d_in[5];
  const float* lt   = (const float*)d_in[6];

  float* out_f    = (float*)d_out;             // output 0: [8192][1024] f32
  float* logits_f = out_f + 8388608;           // output 1: [32][4096][1024] f32

  short* ws    = (short*)d_ws;
  short* Wt    = ws;                 // 4 x 1048576
  short* Xb    = ws + 4194304;       // 8388608 ; reused as oattn
  short* QKVq  = ws + 12582912;      // 8388608 head-major Q (pre-scaled)
  short* Kc    = ws + 20971520;      // [32][1024][64]
  short* Vc    = ws + 23068672;      // [32][1024][64]
  short* Vct   = ws + 25165824;      // [32][64][1024]
  short* oattn = Xb;
  // total 27,262,976 shorts = 54.5 MB

  cvt8<<<dim3(4096), 256, 0, stream>>>(q, Xb);

  convT<<<dim3(16, 16), 256, 0, stream>>>(Wq,   Wt,           1024, 1024);
  convT<<<dim3(16, 16), 256, 0, stream>>>(Wk,   Wt + 1048576, 1024, 1024);
  convT<<<dim3(16, 16), 256, 0, stream>>>(Wv,   Wt + 2097152, 1024, 1024);
  convT<<<dim3(16, 16), 256, 0, stream>>>(Wlin, Wt + 3145728, 1024, 1024);

  // Q projection (head-major epilogue, pre-scaled by exp(-log_temp))
  GemmArgs gq = {};
  gq.A = Xb; gq.Bt = Wt; gq.C = QKVq;
  gq.sA = 1024; gq.sB = 1024; gq.sC = 0;
  gq.zA = 0; gq.zB = 0; gq.zC = 0;
  gq.K = 1024; gq.ltemp = lt; gq.mode = 1;
  gemm_bt<<<dim3(8, 64, 1), 256, 0, stream>>>(gq);

  // K,V projections with fused depthwise conv (z=0 -> Kc, z=1 -> Vc)
  GemmArgs gkv = {};
  gkv.A = Xb; gkv.Bt = Wt + 1048576; gkv.C = Kc; gkv.C2 = Vc;
  gkv.sA = 1024; gkv.sB = 1024; gkv.sC = 0;
  gkv.zA = 0; gkv.zB = 1048576; gkv.zC = 0;
  gkv.K = 1024; gkv.cw = cw; gkv.mode = 2;
  gemm_bt<<<dim3(8, 64, 2), 256, 0, stream>>>(gkv);

  // Vc -> Vct
  transpose2d<<<dim3(1, 16, 32), 256, 0, stream>>>(Vc, Vct, 1024, 64);

  // fused logits (plain f32 stores) + max-free softmax + PV; 32 q/wave
  fused_attn<<<dim3(1024), 256, 0, stream>>>(QKVq, Kc, Vct, logits_f, oattn);

  // out = oattn @ Wlin
  GemmArgs gf = {};
  gf.A = oattn; gf.Bt = Wt + 3145728; gf.Cf = out_f;
  gf.sA = 1024; gf.sB = 1024; gf.sC = 1024;
  gf.zA = 0; gf.zB = 0; gf.zC = 0;
  gf.K = 1024; gf.mode = 0;
  gemm_bt<<<dim3(8, 64, 1), 256, 0, stream>>>(gf);
}